// Round 1
// 532.729 us; speedup vs baseline: 1.0132x; 1.0132x over previous
//
#include <hip/hip_runtime.h>

#define F      128
#define NPAIR  8128   // F*(F-1)/2
#define OUTW   8256   // F + NPAIR
#define NQUAD  (NPAIR / 4)  // 2032 float4 per row

typedef float f4 __attribute__((ext_vector_type(4)));

// XOR-fold bits [6:5] into bits [1:0]: bijective involution on [0,128).
// The pair loop's j-gather walks LDS with stride 4 across lanes
// (lane l reads ~ j0 + 4l), which hits only 8 of 32 banks (8-way
// conflict, ~2.9x serialization). Folding the quadrant bits into the
// low bits spreads the walk across all 32 banks (~2-way = free).
__device__ __forceinline__ int swz(int idx) { return idx ^ (idx >> 5); }

__global__ __launch_bounds__(256) void feat_inter_kernel(
    const float* __restrict__ x, float* __restrict__ out)
{
    __shared__ float xs_lin[F];  // linear: head copy + broadcast i-reads
    __shared__ float xs_swz[F];  // swizzled: stride-4 j-gathers

    const int row = blockIdx.x;
    const int tid = threadIdx.x;
    const float* xr   = x   + (size_t)row * F;
    float*       orow = out + (size_t)row * OUTW;

    if (tid < F) {
        const float v = xr[tid];
        xs_lin[tid]      = v;
        xs_swz[swz(tid)] = v;
    }
    __syncthreads();

    // Head: out[:, :F] = x — 128 floats = 32 f4 stores
    if (tid < 32) {
        f4 v;
        v.x = xs_lin[tid * 4 + 0];
        v.y = xs_lin[tid * 4 + 1];
        v.z = xs_lin[tid * 4 + 2];
        v.w = xs_lin[tid * 4 + 3];
        __builtin_nontemporal_store(v, (f4*)orow + tid);
    }

    // Interactions: flat pair index k in [0, 8128), (i,j) with i<j in
    // row-major triu order. off(i) = i*127 - i*(i-1)/2.
    // Decode i ONCE per quad (sqrt + one-step fixup), then advance
    // (i,j) incrementally over the 4 elements — row lengths are >= 1,
    // so at most one row-advance per element (branchless cndmask).
    f4* odst = (f4*)(orow + F);
    for (int q = tid; q < NQUAD; q += 256) {
        const int k0 = q * 4;
        const float disc = 65025.0f - 8.0f * (float)k0;
        int i = (int)((255.0f - sqrtf(disc)) * 0.5f);
        int offi = i * 127 - ((i * (i - 1)) >> 1);
        if (k0 < offi) {
            --i;
            offi -= 127 - i;            // off(i-1) = off(i) - (127-(i-1))
        } else {
            const int offn = offi + (127 - i);
            if (k0 >= offn) { ++i; offi = offn; }
        }
        int j = i + 1 + (k0 - offi);
        f4 v;
#pragma unroll
        for (int u = 0; u < 4; ++u) {
            const bool adv = (j >= F);   // row boundary inside the quad
            i = adv ? i + 1 : i;
            j = adv ? i + 1 : j;
            v[u] = xs_lin[i] * xs_swz[swz(j)];
            ++j;
        }
        __builtin_nontemporal_store(v, odst + q);
    }
}

extern "C" void kernel_launch(void* const* d_in, const int* in_sizes, int n_in,
                              void* d_out, int out_size, void* d_ws, size_t ws_size,
                              hipStream_t stream) {
    const float* x  = (const float*)d_in[0];
    float*      out = (float*)d_out;
    const int rows = in_sizes[0] / F;  // 16384
    feat_inter_kernel<<<rows, 256, 0, stream>>>(x, out);
}